// Round 3
// baseline (482.666 us; speedup 1.0000x reference)
//
#include <hip/hip_runtime.h>

#define IN 906
#define TT 512
#define NB 128

// ---------------------------------------------------------------------------
__device__ __forceinline__ float fsigm(float x) {
    float e = __builtin_amdgcn_exp2f(-1.4426950408889634f * x);   // exp(-x)
    return __builtin_amdgcn_rcpf(1.f + e);
}
__device__ __forceinline__ float ftanh(float x) {
    float e = __builtin_amdgcn_exp2f(-2.8853900817779268f * x);   // exp(-2x)
    return 2.f * __builtin_amdgcn_rcpf(1.f + e) - 1.f;
}
template <int M>
__device__ __forceinline__ float quad_bcast(float v) {
    constexpr int ctrl = M | (M << 2) | (M << 4) | (M << 6);
    return __int_as_float(
        __builtin_amdgcn_mov_dpp(__float_as_int(v), ctrl, 0xf, 0xf, true));
}

// ---------------------------------------------------------------------------
// GEMM v4: xp = x @ W^T + b1 + b2, stored permuted xp[row][(j&3)*4 + (j>>2)].
//
// Diagnosis of v1/v3 (~57us): TA/request-rate-bound. The [col][row] LDS
// staging made every x wave-load touch 32 rows (64 segments/instr, 8B per
// lane-request) => ~4600 lane-req per CU per chunk ~ 56us, with VALU at
// 1024cyc and LDS (v3) at 2300cyc hidden under it. v2 (LDS-free) had
// perfect coalescing but 8 rows/wave => acc[128], ~200 VGPR, 8 waves/CU,
// no slice pipelining => latency-serial.
//
// v4 = v2's layout with v2's failure fixed:
//   - K across lanes: lane l owns k = s*128 + 2l (+1); 8 serial slices.
//   - 4 rows/wave (not 8): acc[64]; explicit 2-deep ping-pong slice
//     pipeline (wA/xA, wB/xB) => loads of slice s+1 in flight under FMAs
//     of slice s; ~155 VGPR; __launch_bounds__(256,3) => 12 waves/CU.
//   - every load 512B contiguous per wave-instr (~5 segments vs 64).
//   - 63-shuffle fold-reduce (6 steps, fold (r,j) bits into lane bits);
//     no LDS, no __syncthreads.
// Floors: x HBM 238MB/6.3TBs = 37us (binding); W via L2 950MB/34.5TBs =
// 27us (overlapped); VALU ~14us; TA ~21us.
__global__ __launch_bounds__(256, 3)
void gemm_xp(const float* __restrict__ x, const float* __restrict__ W,
             const float* __restrict__ b1, const float* __restrict__ b2,
             float* __restrict__ xp)
{
    const int tid = threadIdx.x;
    const int l   = tid & 63;
    const size_t row0 = (size_t)blockIdx.x * 16 + (size_t)(tid >> 6) * 4;

    float acc[64];                       // acc[r*16 + j]
#pragma unroll
    for (int i = 0; i < 64; ++i) acc[i] = 0.f;

    const int kl = l * 2;

    float2 wA[16], wB[16];
    float2 xA[4],  xB[4];

    auto load_slice = [&](int s, float2 (&wv)[16], float2 (&xv)[4]) {
        const int k = s * 128 + kl;
        if (s < 7) {                              // k <= 894: in range
#pragma unroll
            for (int jj = 0; jj < 16; ++jj)
                wv[jj] = *(const float2*)(W + jj * IN + k);
#pragma unroll
            for (int r = 0; r < 4; ++r)
                xv[r] = *(const float2*)(x + (row0 + r) * IN + k);
        } else {                                  // tail: k valid while < 906
            const bool ok = (k < IN);             // pair-granular (906 even)
            const int  kc = ok ? k : 0;           // clamped, always in-bounds
#pragma unroll
            for (int jj = 0; jj < 16; ++jj) {
                float2 t = *(const float2*)(W + jj * IN + kc);
                wv[jj].x = ok ? t.x : 0.f;        // zero W => product zero
                wv[jj].y = ok ? t.y : 0.f;
            }
#pragma unroll
            for (int r = 0; r < 4; ++r)
                xv[r] = *(const float2*)(x + (row0 + r) * IN + kc);
        }
    };
    auto mac_slice = [&](float2 (&wv)[16], float2 (&xv)[4]) {
#pragma unroll
        for (int r = 0; r < 4; ++r)
#pragma unroll
            for (int jj = 0; jj < 16; ++jj) {
                acc[r * 16 + jj] = fmaf(xv[r].x, wv[jj].x, acc[r * 16 + jj]);
                acc[r * 16 + jj] = fmaf(xv[r].y, wv[jj].y, acc[r * 16 + jj]);
            }
    };

    load_slice(0, wA, xA);
#pragma unroll
    for (int s = 0; s < 8; ++s) {                 // fully unrolled: all
        if (s + 1 < 8) {                          // buffer picks are static
            if (s & 1) load_slice(s + 1, wA, xA);
            else       load_slice(s + 1, wB, xB);
        }
        if (s & 1) mac_slice(wB, xB);
        else       mac_slice(wA, xA);
    }

    // ---- fold-reduce: 64 partials x 64 lanes -> 1 total per lane ----------
    // j bits 0..3 -> lane bits 0..3 (xor 1,2,4,8); r bits -> lane bits 4,5
    // (xor 16,32). Final: lane l holds total for r=(l>>4)&3, j=l&15.
    float u1[32];
#pragma unroll
    for (int i = 0; i < 32; ++i) {
        float lo = acc[2 * i], hi = acc[2 * i + 1];
        float mi = (l & 1) ? hi : lo;
        float ot = (l & 1) ? lo : hi;
        u1[i] = mi + __shfl_xor(ot, 1);
    }
    float u2[16];
#pragma unroll
    for (int i = 0; i < 16; ++i) {
        float lo = u1[2 * i], hi = u1[2 * i + 1];
        float mi = (l & 2) ? hi : lo;
        float ot = (l & 2) ? lo : hi;
        u2[i] = mi + __shfl_xor(ot, 2);
    }
    float u3[8];
#pragma unroll
    for (int i = 0; i < 8; ++i) {
        float lo = u2[2 * i], hi = u2[2 * i + 1];
        float mi = (l & 4) ? hi : lo;
        float ot = (l & 4) ? lo : hi;
        u3[i] = mi + __shfl_xor(ot, 4);
    }
    float u4[4];
#pragma unroll
    for (int i = 0; i < 4; ++i) {
        float lo = u3[2 * i], hi = u3[2 * i + 1];
        float mi = (l & 8) ? hi : lo;
        float ot = (l & 8) ? lo : hi;
        u4[i] = mi + __shfl_xor(ot, 8);
    }
    float u5[2];
#pragma unroll
    for (int i = 0; i < 2; ++i) {
        float lo = u4[2 * i], hi = u4[2 * i + 1];
        float mi = (l & 16) ? hi : lo;
        float ot = (l & 16) ? lo : hi;
        u5[i] = mi + __shfl_xor(ot, 16);
    }
    float tot;
    {
        float lo = u5[0], hi = u5[1];
        float mi = (l & 32) ? hi : lo;
        float ot = (l & 32) ? lo : hi;
        tot = mi + __shfl_xor(ot, 32);
    }

    // ---- writeout: lane l -> row row0+((l>>4)&3), out j = l&15 ------------
    const int jo = l & 15;
    const int g  = (l >> 4) & 3;
    const int pj = (jo & 3) * 4 + (jo >> 2);      // permuted position
    xp[(row0 + (size_t)g) * 16 + pj] = tot + b1[jo] + b2[jo];
}

// ---------------------------------------------------------------------------
// Recurrence kernel: 8 blocks x 256 threads, 16 batches per block.
// wave 0: 512-step forward recurrence (quad per batch, DPP h-broadcast),
//         16-step-deep xp prefetch (covers ~900cyc cross-XCD/HBM latency;
//         depth 4 left steps memory-throttled at ~225cyc vs ~70cyc chain).
// waves 1-3: backward-direction GEMV (f-gate irrelevant, c0=0) -> LDS.
// epilogue (wave 0): backward cell + output projection.
__global__ __launch_bounds__(256)
void frec(const float* __restrict__ xp, const float* __restrict__ x,
          const float* __restrict__ Whh, const float* __restrict__ Wb,
          const float* __restrict__ bb1, const float* __restrict__ bb2,
          const float* __restrict__ Wout, const float* __restrict__ bout,
          float* __restrict__ out)
{
    __shared__ float bg[16][12];
    const int tid = threadIdx.x;

    float h0 = 0.f, h1 = 0.f, h2 = 0.f, h3 = 0.f;

    if (tid >= 64) {
        // ---- backward GEMV: 192 lanes = 16 batches x 12 gate rows ----
        const int gl = tid - 64;          // 0..191
        const int r  = gl >> 4;           // 0..11
        const int bq = gl & 15;
        const int b  = blockIdx.x * 16 + bq;
        const int gr = (r < 4) ? r : r + 4;   // rows: i 0-3, g 8-11, o 12-15
        const float2* __restrict__ xr  = (const float2*)(x + ((size_t)b * TT + (TT - 1)) * IN);
        const float2* __restrict__ wrp = (const float2*)(Wb + gr * IN);
        float s0 = 0.f, s1 = 0.f;
        int j = 0;
        for (; j + 8 <= 453; j += 8) {
#pragma unroll
            for (int u = 0; u < 8; ++u) {
                float2 a = xr[j + u];
                float2 w = wrp[j + u];
                s0 = fmaf(a.x, w.x, s0);
                s1 = fmaf(a.y, w.y, s1);
            }
        }
        for (; j < 453; ++j) {
            float2 a = xr[j];
            float2 w = wrp[j];
            s0 = fmaf(a.x, w.x, s0);
            s1 = fmaf(a.y, w.y, s1);
        }
        bg[bq][r] = s0 + s1 + bb1[gr] + bb2[gr];
    } else {
        // ---- forward recurrence ----
        const int k = tid & 3;
        const int b = blockIdx.x * 16 + (tid >> 2);

        float Wi[4], Wf4[4], Wg[4], Wo[4];
#pragma unroll
        for (int m = 0; m < 4; ++m) {
            Wi[m]  = Whh[(k)      * 4 + m];
            Wf4[m] = Whh[(4 + k)  * 4 + m];
            Wg[m]  = Whh[(8 + k)  * 4 + m];
            Wo[m]  = Whh[(12 + k) * 4 + m];
        }

        const float4* __restrict__ xq = (const float4*)xp;
        const size_t base = (size_t)b * TT * 4 + k;

        float4 pf[16];
#pragma unroll
        for (int i = 0; i < 16; ++i) pf[i] = xq[base + (size_t)i * 4];

        float c = 0.f;
        for (int t = 0; t < TT; t += 16) {
#pragma unroll
            for (int u = 0; u < 16; ++u) {
                float4 cur = pf[u];
                int tn = t + 16 + u;
                int tc = (tn < TT) ? tn : (TT - 1);
                pf[u] = xq[base + (size_t)tc * 4];   // prefetch 16 ahead

                float gi = cur.x + h0 * Wi[0]  + h1 * Wi[1]  + h2 * Wi[2]  + h3 * Wi[3];
                float gf = cur.y + h0 * Wf4[0] + h1 * Wf4[1] + h2 * Wf4[2] + h3 * Wf4[3];
                float gg = cur.z + h0 * Wg[0]  + h1 * Wg[1]  + h2 * Wg[2]  + h3 * Wg[3];
                float go = cur.w + h0 * Wo[0]  + h1 * Wo[1]  + h2 * Wo[2]  + h3 * Wo[3];

                float si = fsigm(gi);
                float sf = fsigm(gf);
                float tg = ftanh(gg);
                float so = fsigm(go);

                c = sf * c + si * tg;
                float h = so * ftanh(c);

                h0 = quad_bcast<0>(h);
                h1 = quad_bcast<1>(h);
                h2 = quad_bcast<2>(h);
                h3 = quad_bcast<3>(h);
            }
        }
    }

    __syncthreads();

    if (tid < 64) {
        const int k  = tid & 3;
        const int bq = tid >> 2;
        const int b  = blockIdx.x * 16 + bq;

        float gib = bg[bq][k];
        float ggb = bg[bq][4 + k];
        float gob = bg[bq][8 + k];
        float hbk = fsigm(gob) * ftanh(fsigm(gib) * ftanh(ggb));
        float hb0 = quad_bcast<0>(hbk);
        float hb1 = quad_bcast<1>(hbk);
        float hb2 = quad_bcast<2>(hbk);
        float hb3 = quad_bcast<3>(hbk);

        float o0 = bout[0]
                 + h0  * Wout[0]  + h1  * Wout[1]  + h2  * Wout[2]  + h3  * Wout[3]
                 + hb0 * Wout[4]  + hb1 * Wout[5]  + hb2 * Wout[6]  + hb3 * Wout[7];
        float o1 = bout[1]
                 + h0  * Wout[8]  + h1  * Wout[9]  + h2  * Wout[10] + h3  * Wout[11]
                 + hb0 * Wout[12] + hb1 * Wout[13] + hb2 * Wout[14] + hb3 * Wout[15];

        if (k == 0) {
            out[b * 2 + 0] = o0;
            out[b * 2 + 1] = o1;
        }
    }
}

// ---------------------------------------------------------------------------
extern "C" void kernel_launch(void* const* d_in, const int* in_sizes, int n_in,
                              void* d_out, int out_size, void* d_ws, size_t ws_size,
                              hipStream_t stream)
{
    const float* x    = (const float*)d_in[0];
    const float* Wihf = (const float*)d_in[1];
    const float* Whhf = (const float*)d_in[2];
    const float* bihf = (const float*)d_in[3];
    const float* bhhf = (const float*)d_in[4];
    const float* Wihb = (const float*)d_in[5];
    const float* bihb = (const float*)d_in[7];
    const float* bhhb = (const float*)d_in[8];
    const float* Wout = (const float*)d_in[9];
    const float* bout = (const float*)d_in[10];

    float* xp = (float*)d_ws;   // 65536 rows x 16 floats = 4,194,304 B exactly

    // 65536 rows / (4 waves x 4 rows) = 4096 blocks
    gemm_xp<<<4096, 256, 0, stream>>>(x, Wihf, bihf, bhhf, xp);
    frec<<<8, 256, 0, stream>>>(xp, x, Whhf, Wihb, bihb, bhhb, Wout, bout,
                                (float*)d_out);
}